// Round 6
// baseline (5608.857 us; speedup 1.0000x reference)
//
#include <hip/hip_runtime.h>

// ---------------------------------------------------------------------------
// LinkPredModel: 2-layer GraphSAGE (mean aggr) + dot-product link scoring.
// N=100000 nodes, D=H=128, E=3.2M edges, L=200k label pairs.
// Round 6: aggregation as LDS-accumulating SpMM. Edges per 128-node segment
// are counting-sorted by src>>9 so all concurrent blocks sweep the feature
// table monotonically (L2-resident window) instead of random 64B gathers.
// ---------------------------------------------------------------------------

#define D128 128
#define BSHIFT 9          // 512 nodes per bucket (phase A)
#define BNODES 512

typedef __bf16 bf16x8 __attribute__((ext_vector_type(8)));
typedef float  f32x4  __attribute__((ext_vector_type(4)));

__device__ inline unsigned short f2bf(float f) {
    unsigned u = __float_as_uint(f);
    u = u + 0x7FFF + ((u >> 16) & 1);   // round-to-nearest-even
    return (unsigned short)(u >> 16);
}
__device__ inline float bf2f(unsigned short s) {
    return __uint_as_float(((unsigned)s) << 16);
}
__device__ inline unsigned packbf2(float lo, float hi) {
    return (unsigned)f2bf(lo) | ((unsigned)f2bf(hi) << 16);
}

// ---------------- fp32 -> bf16 cast (4 elems/thread) ----------------

__global__ void cast_kernel(const float* __restrict__ in, unsigned short* __restrict__ out,
                            int n4) {
    int i = blockIdx.x * blockDim.x + threadIdx.x;
    if (i >= n4) return;
    float4 v = ((const float4*)in)[i];
    ushort4 o;
    o.x = f2bf(v.x); o.y = f2bf(v.y); o.z = f2bf(v.z); o.w = f2bf(v.w);
    ((ushort4*)out)[i] = o;
}

// ---------------- weight repack into MFMA B-fragment layout ----------------

__global__ void repack_kernel(const float* __restrict__ W1l, const float* __restrict__ W1r,
                              const float* __restrict__ W2l, const float* __restrict__ W2r,
                              unsigned short* __restrict__ packed) {
    int tid = blockIdx.x * blockDim.x + threadIdx.x;  // [0, 65536)
    int layer = tid >> 15;
    int r = tid & 32767;
    int j    = r & 7;
    int lane = (r >> 3) & 63;
    int nt   = (r >> 9) & 7;
    int kc   = (r >> 12) & 7;
    int k   = kc * 32 + ((lane >> 4) << 3) + j;
    int col = nt * 16 + (lane & 15);
    const float* Wl = layer ? W2l : W1l;
    const float* Wr = layer ? W2r : W1r;
    float v = (k < 128) ? Wl[k * 128 + col] : Wr[(k - 128) * 128 + col];
    packed[tid] = f2bf(v);
}

// ---------------- CSR build: two-level bucket counting sort ----------------

__global__ void hist_kernel(const int* __restrict__ dst, int* __restrict__ gcnt,
                            int E, int NB) {
    __shared__ int h[256];
    int t = threadIdx.x;
    h[t] = 0;
    __syncthreads();
    int base = blockIdx.x * 8192;
#pragma unroll
    for (int k = 0; k < 32; ++k) {
        int e = base + k * 256 + t;
        if (e < E) atomicAdd(&h[dst[e] >> BSHIFT], 1);
    }
    __syncthreads();
    if (t < NB && h[t]) atomicAdd(&gcnt[t], h[t]);
}

__global__ void bucket_scan(const int* __restrict__ gcnt, int* __restrict__ bucket_base,
                            int* __restrict__ bucket_cur, int* __restrict__ rowptr,
                            int NB, int N, int E) {
    __shared__ int sc[256];
    __shared__ int orig[256];
    int t = threadIdx.x;
    int v = (t < NB) ? gcnt[t] : 0;
    orig[t] = v;
    sc[t] = v;
    __syncthreads();
    for (int off = 1; off < 256; off <<= 1) {
        int a = (t >= off) ? sc[t - off] : 0;
        __syncthreads();
        sc[t] += a;
        __syncthreads();
    }
    int ex = sc[t] - orig[t];
    if (t < NB) { bucket_base[t] = ex; bucket_cur[t] = ex; }
    if (t == 0) { bucket_base[NB] = E; rowptr[N] = E; }
}

// packed edge word (phase A): (src << 9) | (dst & 511); fits in 26 bits.
__global__ void scatter_kernel(const int* __restrict__ src, const int* __restrict__ dst,
                               int* __restrict__ bucket_cur, int* __restrict__ pairs,
                               int E, int NB) {
    __shared__ int hist[256], lscan[256], gbase[256];
    __shared__ int lsrc[1024], ldst[1024];
    int t = threadIdx.x;
    hist[t] = 0;
    __syncthreads();
    int base = blockIdx.x * 1024;
    int total = E - base; if (total > 1024) total = 1024;

    int ms[4], md[4], mb[4], mr[4];
#pragma unroll
    for (int k = 0; k < 4; ++k) {
        int i = k * 256 + t;
        int e = base + i;
        mb[k] = -1;
        if (i < total) {
            ms[k] = src[e];
            md[k] = dst[e];
            mb[k] = md[k] >> BSHIFT;
            mr[k] = atomicAdd(&hist[mb[k]], 1);
        }
    }
    __syncthreads();
    lscan[t] = hist[t];
    __syncthreads();
    for (int off = 1; off < 256; off <<= 1) {
        int a = (t >= off) ? lscan[t - off] : 0;
        __syncthreads();
        lscan[t] += a;
        __syncthreads();
    }
    lscan[t] -= hist[t];
    if (t < NB && hist[t] > 0) gbase[t] = atomicAdd(&bucket_cur[t], hist[t]);
    __syncthreads();
#pragma unroll
    for (int k = 0; k < 4; ++k) {
        if (mb[k] >= 0) {
            int idx = lscan[mb[k]] + mr[k];
            lsrc[idx] = ms[k];
            ldst[idx] = md[k];
        }
    }
    __syncthreads();
#pragma unroll
    for (int k = 0; k < 4; ++k) {
        int i = k * 256 + t;
        if (i < total) {
            int d = ldst[i];
            int b = d >> BSHIFT;
            int pos = gbase[b] + (i - lscan[b]);
            pairs[pos] = (lsrc[i] << BSHIFT) | (d & (BNODES - 1));
        }
    }
}

// Phase B: per 512-node bucket counting sort by dst -> rowptr + packed srcs
// word (src<<7 | dst&127) so 128-node SpMM segments know local dst.
__global__ void bucket_fill(const int* __restrict__ pairs, const int* __restrict__ bucket_base,
                            int* __restrict__ rowptr, int* __restrict__ srcs, int N) {
    __shared__ int hist[BNODES], excl[BNODES], sc[BNODES];
    int b = blockIdx.x;
    int t = threadIdx.x;      // blockDim = 512
    int node0 = b << BSHIFT;
    int pbeg = bucket_base[b];
    int pend = bucket_base[b + 1];
    hist[t] = 0;
    __syncthreads();
    for (int p = pbeg + t; p < pend; p += BNODES) {
        atomicAdd(&hist[pairs[p] & (BNODES - 1)], 1);
    }
    __syncthreads();
    sc[t] = hist[t];
    __syncthreads();
    for (int off = 1; off < BNODES; off <<= 1) {
        int a = (t >= off) ? sc[t - off] : 0;
        __syncthreads();
        sc[t] += a;
        __syncthreads();
    }
    excl[t] = sc[t] - hist[t];
    int node = node0 + t;
    if (node < N) rowptr[node] = pbeg + excl[t];
    __syncthreads();
    hist[t] = 0;
    __syncthreads();
    for (int p = pbeg + t; p < pend; p += BNODES) {
        int w = pairs[p];
        int dl = w & (BNODES - 1);
        int c = atomicAdd(&hist[dl], 1);
        int srcn = ((unsigned)w) >> BSHIFT;
        srcs[pbeg + excl[dl] + c] = (srcn << 7) | (dl & 127);
    }
}

// Phase C: per 128-node segment, counting-sort edge words by src>>9 so the
// SpMM sweeps the feature table monotonically (512-row windows).
__global__ void sort2_kernel(const int* __restrict__ rowptr, const int* __restrict__ srcs,
                             int* __restrict__ srcs2, int N) {
    __shared__ int hist[256], sc[256], cur[256];
    int b = blockIdx.x;
    int t = threadIdx.x;      // blockDim = 256
    int r0 = b * 128;
    int r1 = r0 + 128; if (r1 > N) r1 = N;
    int ebeg = rowptr[r0];
    int eend = rowptr[r1];
    hist[t] = 0;
    __syncthreads();
    for (int i = ebeg + t; i < eend; i += 256) {
        atomicAdd(&hist[((unsigned)srcs[i]) >> 16], 1);   // bin = src>>9
    }
    __syncthreads();
    sc[t] = hist[t];
    __syncthreads();
    for (int off = 1; off < 256; off <<= 1) {
        int a = (t >= off) ? sc[t - off] : 0;
        __syncthreads();
        sc[t] += a;
        __syncthreads();
    }
    cur[t] = ebeg + sc[t] - hist[t];   // exclusive cursor
    __syncthreads();
    for (int i = ebeg + t; i < eend; i += 256) {
        int w = srcs[i];
        int pos = atomicAdd(&cur[((unsigned)w) >> 16], 1);
        srcs2[pos] = w;
    }
}

// ---------------- SpMM aggregation: 128 dst rows per block, LDS fp32 acc ----
// Per edge: 64 lanes load one 256B row (uint = 2 bf16 cols per lane), then
// 2 LDS float atomic adds into acc[dst_local][*]. Edges sorted by src>>9 =>
// concurrent blocks sweep the table; window stays L2-resident.

__global__ void spmm_kernel(const int* __restrict__ rowptr, const int* __restrict__ srcs2,
                            const unsigned* __restrict__ feat, unsigned* __restrict__ out,
                            int N) {
    __shared__ float acc[128 * 128];   // 64 KB
    int t = threadIdx.x;               // blockDim = 256
    int wid = t >> 6;
    int lane = t & 63;

    float4 z = make_float4(0.f, 0.f, 0.f, 0.f);
#pragma unroll
    for (int k = 0; k < 16; ++k) ((float4*)acc)[t + k * 256] = z;

    int r0 = blockIdx.x * 128;
    int r1 = r0 + 128; if (r1 > N) r1 = N;
    int ebeg = rowptr[r0];
    int eend = rowptr[r1];
    __syncthreads();

    for (int i0 = ebeg + wid * 8; i0 < eend; i0 += 32) {
        int ws[8];
        unsigned v[8];
        int dl[8];
        if (i0 + 8 <= eend) {
#pragma unroll
            for (int k = 0; k < 8; ++k) ws[k] = srcs2[i0 + k];
#pragma unroll
            for (int k = 0; k < 8; ++k) {
                v[k] = feat[(size_t)(((unsigned)ws[k]) >> 7) * 64 + lane];
                dl[k] = ws[k] & 127;
            }
#pragma unroll
            for (int k = 0; k < 8; ++k) {
                atomicAdd(&acc[dl[k] * 128 + 2 * lane],     __uint_as_float(v[k] << 16));
                atomicAdd(&acc[dl[k] * 128 + 2 * lane + 1], __uint_as_float(v[k] & 0xFFFF0000u));
            }
        } else {
            int n = eend - i0;
#pragma unroll
            for (int k = 0; k < 8; ++k) {
                if (k < n) {
                    int w = srcs2[i0 + k];
                    unsigned vv = feat[(size_t)(((unsigned)w) >> 7) * 64 + lane];
                    int d = w & 127;
                    atomicAdd(&acc[d * 128 + 2 * lane],     __uint_as_float(vv << 16));
                    atomicAdd(&acc[d * 128 + 2 * lane + 1], __uint_as_float(vv & 0xFFFF0000u));
                }
            }
        }
    }
    __syncthreads();

    // epilogue: divide by degree, pack bf16, coalesced row writes (32 rows/wave)
#pragma unroll 4
    for (int r = wid * 32; r < wid * 32 + 32; ++r) {
        int node = r0 + r;
        if (node >= N) break;
        int deg = rowptr[node + 1] - rowptr[node];
        float inv = deg > 0 ? 1.0f / (float)deg : 0.f;
        float lo = acc[r * 128 + 2 * lane] * inv;
        float hi = acc[r * 128 + 2 * lane + 1] * inv;
        out[(size_t)node * 64 + lane] = packbf2(lo, hi);
    }
}

// ---------------- MFMA dual-GEMM: out = act([A|F] @ Wp + b) ----------------

template <bool LEAKY>
__global__ void mm_kernel(const unsigned short* __restrict__ A,
                          const unsigned short* __restrict__ F,
                          const unsigned short* __restrict__ Wp,
                          const float* __restrict__ bias,
                          unsigned short* __restrict__ out, int N) {
    int wid = threadIdx.x >> 6;
    int lane = threadIdx.x & 63;
    int quad = lane >> 4;
    int m0 = (blockIdx.x * 4 + wid) * 32;

    int rowA0 = m0 + (lane & 15);
    int rowA1 = rowA0 + 16;
    if (rowA0 > N - 1) rowA0 = N - 1;
    if (rowA1 > N - 1) rowA1 = N - 1;

    f32x4 acc[2][8];
#pragma unroll
    for (int t = 0; t < 2; ++t)
#pragma unroll
        for (int nt = 0; nt < 8; ++nt) acc[t][nt] = (f32x4){0.f, 0.f, 0.f, 0.f};

#pragma unroll
    for (int kc = 0; kc < 8; ++kc) {
        const unsigned short* src = (kc < 4) ? (A + kc * 32) : (F + (kc - 4) * 32);
        bf16x8 af0 = *(const bf16x8*)(src + (size_t)rowA0 * D128 + quad * 8);
        bf16x8 af1 = *(const bf16x8*)(src + (size_t)rowA1 * D128 + quad * 8);
        const unsigned short* wp = Wp + ((size_t)kc * 8) * 512 + lane * 8;
#pragma unroll
        for (int nt = 0; nt < 8; ++nt) {
            bf16x8 bf = *(const bf16x8*)(wp + nt * 512);
            acc[0][nt] = __builtin_amdgcn_mfma_f32_16x16x32_bf16(af0, bf, acc[0][nt], 0, 0, 0);
            acc[1][nt] = __builtin_amdgcn_mfma_f32_16x16x32_bf16(af1, bf, acc[1][nt], 0, 0, 0);
        }
    }

#pragma unroll
    for (int nt = 0; nt < 8; ++nt) {
        int col = nt * 16 + (lane & 15);
        float bv = bias[col];
#pragma unroll
        for (int t = 0; t < 2; ++t) {
#pragma unroll
            for (int r = 0; r < 4; ++r) {
                int row = m0 + t * 16 + quad * 4 + r;
                if (row < N) {
                    float v = acc[t][nt][r] + bv;
                    if (LEAKY) v = v >= 0.f ? v : 0.2f * v;
                    out[(size_t)row * D128 + col] = f2bf(v);
                }
            }
        }
    }
}

// ---------------- link scoring: 4 pairs per wave (8 gathers in flight) ----------------

__global__ void score_kernel(const int* __restrict__ eli, const unsigned short* __restrict__ h,
                             float* __restrict__ out, int L) {
    int wave = threadIdx.x >> 6;
    int lane = threadIdx.x & 63;
    int l0 = (blockIdx.x * 4 + wave) * 4;
    if (l0 >= L) return;
    const ushort2* h2 = (const ushort2*)h;
    int a[4], b[4];
#pragma unroll
    for (int k = 0; k < 4; ++k) {
        int l = l0 + k;
        if (l > L - 1) l = L - 1;
        a[k] = eli[l];
        b[k] = eli[L + l];
    }
    float p[4];
#pragma unroll
    for (int k = 0; k < 4; ++k) {
        ushort2 u = h2[(size_t)a[k] * 64 + lane];
        ushort2 v = h2[(size_t)b[k] * 64 + lane];
        p[k] = bf2f(u.x) * bf2f(v.x) + bf2f(u.y) * bf2f(v.y);
    }
#pragma unroll
    for (int off = 32; off > 0; off >>= 1) {
#pragma unroll
        for (int k = 0; k < 4; ++k) p[k] += __shfl_down(p[k], off, 64);
    }
    if (lane == 0) {
#pragma unroll
        for (int k = 0; k < 4; ++k) {
            if (l0 + k < L) out[l0 + k] = p[k];
        }
    }
}

// ---------------- host launch ----------------

extern "C" void kernel_launch(void* const* d_in, const int* in_sizes, int n_in,
                              void* d_out, int out_size, void* d_ws, size_t ws_size,
                              hipStream_t stream) {
    const float* x   = (const float*)d_in[0];
    const int*   ei  = (const int*)d_in[1];
    const int*   eli = (const int*)d_in[2];
    const float* W1l = (const float*)d_in[3];
    const float* b1  = (const float*)d_in[4];
    const float* W1r = (const float*)d_in[5];
    const float* W2l = (const float*)d_in[6];
    const float* b2  = (const float*)d_in[7];
    const float* W2r = (const float*)d_in[8];

    const int N = in_sizes[0] / D128;
    const int E = in_sizes[1] / 2;
    const int L = in_sizes[2] / 2;
    const int* srcp = ei;
    const int* dstp = ei + E;
    const int NB = (N + BNODES - 1) >> BSHIFT;   // 196 for N=100000 (<=256)
    const int NSEG = (N + 127) / 128;            // 782 SpMM segments

    char* ws = (char*)d_ws;
    size_t off = 0;
    auto alloc = [&](size_t bytes) -> void* {
        void* p = ws + off;
        off += (bytes + 255) & ~(size_t)255;
        return p;
    };
    int*   rowptr = (int*)alloc((size_t)(N + 1) * sizeof(int));
    int*   gcnt   = (int*)alloc(256 * sizeof(int));
    int*   bbase  = (int*)alloc(257 * sizeof(int));
    int*   bcur   = (int*)alloc(256 * sizeof(int));
    int*   pairs  = (int*)alloc((size_t)E * sizeof(int));
    int*   srcs   = (int*)alloc((size_t)E * sizeof(int));
    int*   srcs2  = (int*)alloc(((size_t)E + 8) * sizeof(int));
    unsigned short* xb   = (unsigned short*)alloc((size_t)N * D128 * 2);
    unsigned short* aggb = (unsigned short*)alloc((size_t)N * D128 * 2);
    unsigned short* h1b  = (unsigned short*)alloc((size_t)N * D128 * 2);
    unsigned short* h2b  = (unsigned short*)alloc((size_t)N * D128 * 2);
    unsigned short* Wp   = (unsigned short*)alloc(2 * 32768 * 2);
    (void)ws_size; (void)n_in; (void)out_size;

    // --- casts + weight repack ---
    int n4 = N * D128 / 4;
    cast_kernel<<<(n4 + 255) / 256, 256, 0, stream>>>(x, xb, n4);
    repack_kernel<<<65536 / 256, 256, 0, stream>>>(W1l, W1r, W2l, W2r, Wp);

    // --- CSR build (bucket counting sort) + src-sweep edge order ---
    hipMemsetAsync(gcnt, 0, 256 * sizeof(int), stream);
    hist_kernel<<<(E + 8191) / 8192, 256, 0, stream>>>(dstp, gcnt, E, NB);
    bucket_scan<<<1, 256, 0, stream>>>(gcnt, bbase, bcur, rowptr, NB, N, E);
    scatter_kernel<<<(E + 1023) / 1024, 256, 0, stream>>>(srcp, dstp, bcur, pairs, E, NB);
    bucket_fill<<<NB, BNODES, 0, stream>>>(pairs, bbase, rowptr, srcs, N);
    sort2_kernel<<<NSEG, 256, 0, stream>>>(rowptr, srcs, srcs2, N);

    // --- layer 1 ---
    spmm_kernel<<<NSEG, 256, 0, stream>>>(rowptr, srcs2, (const unsigned*)xb,
                                          (unsigned*)aggb, N);
    mm_kernel<true><<<(N + 127) / 128, 256, 0, stream>>>(aggb, xb, Wp, b1, h1b, N);

    // --- layer 2 ---
    spmm_kernel<<<NSEG, 256, 0, stream>>>(rowptr, srcs2, (const unsigned*)h1b,
                                          (unsigned*)aggb, N);
    mm_kernel<false><<<(N + 127) / 128, 256, 0, stream>>>(aggb, h1b, Wp + 32768, b2, h2b, N);

    // --- scoring ---
    score_kernel<<<(L + 15) / 16, 256, 0, stream>>>(eli, h2b, (float*)d_out, L);
}

// Round 7
// 463.959 us; speedup vs baseline: 12.0891x; 12.0891x over previous
//
#include <hip/hip_runtime.h>
#include <hip/hip_fp16.h>

// ---------------------------------------------------------------------------
// LinkPredModel: 2-layer GraphSAGE (mean aggr) + dot-product link scoring.
// N=100000 nodes, D=H=128, E=3.2M edges, L=200k label pairs.
// Round 7: revert R6's LDS-atomic SpMM (25x regression). Back to R5 structure;
// gather tables for aggregation stored as fp8 e5m2 (= truncated fp16: decode
// is byte<<8 + v_cvt_f32_f16), halving the L2-miss-path bytes that R4/R5
// showed to be the binding constraint (time pinned while MLP doubled).
// ---------------------------------------------------------------------------

#define D128 128
#define BSHIFT 9          // 512 nodes per bucket
#define BNODES 512

typedef __bf16 bf16x8 __attribute__((ext_vector_type(8)));
typedef float  f32x4  __attribute__((ext_vector_type(4)));

__device__ inline unsigned short f2bf(float f) {
    unsigned u = __float_as_uint(f);
    u = u + 0x7FFF + ((u >> 16) & 1);   // round-to-nearest-even
    return (unsigned short)(u >> 16);
}
__device__ inline float bf2f(unsigned short s) {
    return __uint_as_float(((unsigned)s) << 16);
}
__device__ inline unsigned packbf2(float lo, float hi) {
    return (unsigned)f2bf(lo) | ((unsigned)f2bf(hi) << 16);
}
// fp8 e5m2 = top byte of fp16 (RNE truncation on encode; decode exact).
__device__ inline unsigned char f2e5(float f) {
    unsigned short h = __half_as_ushort(__float2half(f));  // RNE f32->fp16
    h = (unsigned short)(h + 0x7F + ((h >> 8) & 1));       // RNE fp16->e5m2
    return (unsigned char)(h >> 8);
}
__device__ inline float e5lo(unsigned hw) {                // bits[15:8] = fp8
    return __half2float(__ushort_as_half((unsigned short)(hw & 0xFF00u)));
}

// ---------------- fp32 -> bf16 + fp8 cast (4 elems/thread) ----------------

__global__ void cast_kernel(const float* __restrict__ in, unsigned short* __restrict__ outb,
                            unsigned char* __restrict__ out8, int n4) {
    int i = blockIdx.x * blockDim.x + threadIdx.x;
    if (i >= n4) return;
    float4 v = ((const float4*)in)[i];
    ushort4 ob;
    ob.x = f2bf(v.x); ob.y = f2bf(v.y); ob.z = f2bf(v.z); ob.w = f2bf(v.w);
    ((ushort4*)outb)[i] = ob;
    unsigned p = (unsigned)f2e5(v.x) | ((unsigned)f2e5(v.y) << 8) |
                 ((unsigned)f2e5(v.z) << 16) | ((unsigned)f2e5(v.w) << 24);
    ((unsigned*)out8)[i] = p;
}

// ---------------- weight repack into MFMA B-fragment layout ----------------

__global__ void repack_kernel(const float* __restrict__ W1l, const float* __restrict__ W1r,
                              const float* __restrict__ W2l, const float* __restrict__ W2r,
                              unsigned short* __restrict__ packed) {
    int tid = blockIdx.x * blockDim.x + threadIdx.x;  // [0, 65536)
    int layer = tid >> 15;
    int r = tid & 32767;
    int j    = r & 7;
    int lane = (r >> 3) & 63;
    int nt   = (r >> 9) & 7;
    int kc   = (r >> 12) & 7;
    int k   = kc * 32 + ((lane >> 4) << 3) + j;
    int col = nt * 16 + (lane & 15);
    const float* Wl = layer ? W2l : W1l;
    const float* Wr = layer ? W2r : W1r;
    float v = (k < 128) ? Wl[k * 128 + col] : Wr[(k - 128) * 128 + col];
    packed[tid] = f2bf(v);
}

// ---------------- CSR build: two-level bucket counting sort ----------------

__global__ void hist_kernel(const int* __restrict__ dst, int* __restrict__ gcnt,
                            int E, int NB) {
    __shared__ int h[256];
    int t = threadIdx.x;
    h[t] = 0;
    __syncthreads();
    int base = blockIdx.x * 8192;
#pragma unroll
    for (int k = 0; k < 32; ++k) {
        int e = base + k * 256 + t;
        if (e < E) atomicAdd(&h[dst[e] >> BSHIFT], 1);
    }
    __syncthreads();
    if (t < NB && h[t]) atomicAdd(&gcnt[t], h[t]);
}

__global__ void bucket_scan(const int* __restrict__ gcnt, int* __restrict__ bucket_base,
                            int* __restrict__ bucket_cur, int* __restrict__ rowptr,
                            int NB, int N, int E) {
    __shared__ int sc[256];
    __shared__ int orig[256];
    int t = threadIdx.x;
    int v = (t < NB) ? gcnt[t] : 0;
    orig[t] = v;
    sc[t] = v;
    __syncthreads();
    for (int off = 1; off < 256; off <<= 1) {
        int a = (t >= off) ? sc[t - off] : 0;
        __syncthreads();
        sc[t] += a;
        __syncthreads();
    }
    int ex = sc[t] - orig[t];
    if (t < NB) { bucket_base[t] = ex; bucket_cur[t] = ex; }
    if (t == 0) { bucket_base[NB] = E; rowptr[N] = E; }
}

// packed edge word: (src << 9) | (dst & 511); src < 2^17, so fits in 26 bits.
__global__ void scatter_kernel(const int* __restrict__ src, const int* __restrict__ dst,
                               int* __restrict__ bucket_cur, int* __restrict__ pairs,
                               int E, int NB) {
    __shared__ int hist[256], lscan[256], gbase[256];
    __shared__ int lsrc[1024], ldst[1024];
    int t = threadIdx.x;
    hist[t] = 0;
    __syncthreads();
    int base = blockIdx.x * 1024;
    int total = E - base; if (total > 1024) total = 1024;

    int ms[4], md[4], mb[4], mr[4];
#pragma unroll
    for (int k = 0; k < 4; ++k) {
        int i = k * 256 + t;
        int e = base + i;
        mb[k] = -1;
        if (i < total) {
            ms[k] = src[e];
            md[k] = dst[e];
            mb[k] = md[k] >> BSHIFT;
            mr[k] = atomicAdd(&hist[mb[k]], 1);
        }
    }
    __syncthreads();
    lscan[t] = hist[t];
    __syncthreads();
    for (int off = 1; off < 256; off <<= 1) {
        int a = (t >= off) ? lscan[t - off] : 0;
        __syncthreads();
        lscan[t] += a;
        __syncthreads();
    }
    lscan[t] -= hist[t];
    if (t < NB && hist[t] > 0) gbase[t] = atomicAdd(&bucket_cur[t], hist[t]);
    __syncthreads();
#pragma unroll
    for (int k = 0; k < 4; ++k) {
        if (mb[k] >= 0) {
            int idx = lscan[mb[k]] + mr[k];
            lsrc[idx] = ms[k];
            ldst[idx] = md[k];
        }
    }
    __syncthreads();
#pragma unroll
    for (int k = 0; k < 4; ++k) {
        int i = k * 256 + t;
        if (i < total) {
            int d = ldst[i];
            int b = d >> BSHIFT;
            int pos = gbase[b] + (i - lscan[b]);
            pairs[pos] = (lsrc[i] << BSHIFT) | (d & (BNODES - 1));
        }
    }
}

__global__ void bucket_fill(const int* __restrict__ pairs, const int* __restrict__ bucket_base,
                            int* __restrict__ rowptr, int* __restrict__ srcs, int N) {
    __shared__ int hist[BNODES], excl[BNODES], sc[BNODES];
    int b = blockIdx.x;
    int t = threadIdx.x;      // blockDim = 512
    int node0 = b << BSHIFT;
    int pbeg = bucket_base[b];
    int pend = bucket_base[b + 1];
    hist[t] = 0;
    __syncthreads();
    for (int p = pbeg + t; p < pend; p += BNODES) {
        atomicAdd(&hist[pairs[p] & (BNODES - 1)], 1);
    }
    __syncthreads();
    sc[t] = hist[t];
    __syncthreads();
    for (int off = 1; off < BNODES; off <<= 1) {
        int a = (t >= off) ? sc[t - off] : 0;
        __syncthreads();
        sc[t] += a;
        __syncthreads();
    }
    excl[t] = sc[t] - hist[t];
    int node = node0 + t;
    if (node < N) rowptr[node] = pbeg + excl[t];
    __syncthreads();
    hist[t] = 0;
    __syncthreads();
    for (int p = pbeg + t; p < pend; p += BNODES) {
        int w = pairs[p];
        int dl = w & (BNODES - 1);
        int c = atomicAdd(&hist[dl], 1);
        srcs[pbeg + excl[dl] + c] = ((unsigned)w) >> BSHIFT;
    }
}

// ---------------- mean aggregation: one wave per node, fp8 rows ----------------
// fp8 row = 128B: quarter-wave (16 lanes x uint2) covers one row => one load
// instr fetches 4 edge-rows (512B). 16-edge unroll => 4 independent loads in
// flight. Decode: byte<<8 = fp16 bits -> v_cvt_f32_f16 (exact).

__device__ inline void accum8f8(float* A, uint2 v) {
    A[0] += e5lo(v.x << 8);
    A[1] += e5lo(v.x);
    A[2] += e5lo(v.x >> 8);
    A[3] += e5lo(v.x >> 16);
    A[4] += e5lo(v.y << 8);
    A[5] += e5lo(v.y);
    A[6] += e5lo(v.y >> 8);
    A[7] += e5lo(v.y >> 16);
}

__global__ void agg_kernel(const int* __restrict__ rowptr, const int* __restrict__ srcs,
                           const unsigned char* __restrict__ feat8,
                           unsigned short* __restrict__ out, int N) {
    int wave = threadIdx.x >> 6;
    int lane = threadIdx.x & 63;
    int q  = lane >> 4;    // quarter 0..3 -> edge slot within group of 4
    int ql = lane & 15;    // 8B chunk within 128B row
    int n = blockIdx.x * 4 + wave;
    if (n >= N) return;
    int beg = rowptr[n];
    int end = rowptr[n + 1];
    const uint2* f = (const uint2*)feat8;   // 16 uint2 per 128B row

    float A0[8], A1[8], A2[8], A3[8];
#pragma unroll
    for (int k = 0; k < 8; ++k) { A0[k] = 0.f; A1[k] = 0.f; A2[k] = 0.f; A3[k] = 0.f; }

    int j = beg;
    for (; j + 16 <= end; j += 16) {
        int e0 = srcs[j + q];
        int e1 = srcs[j + 4 + q];
        int e2 = srcs[j + 8 + q];
        int e3 = srcs[j + 12 + q];
        uint2 v0 = f[(size_t)e0 * 16 + ql];
        uint2 v1 = f[(size_t)e1 * 16 + ql];
        uint2 v2 = f[(size_t)e2 * 16 + ql];
        uint2 v3 = f[(size_t)e3 * 16 + ql];
        accum8f8(A0, v0);
        accum8f8(A1, v1);
        accum8f8(A2, v2);
        accum8f8(A3, v3);
    }
    for (; j + 4 <= end; j += 4) {
        int e = srcs[j + q];
        uint2 v = f[(size_t)e * 16 + ql];
        accum8f8(A0, v);
    }
    int rem = end - j;
    if (q < rem) {
        int e = srcs[j + q];
        uint2 v = f[(size_t)e * 16 + ql];
        accum8f8(A1, v);
    }

#pragma unroll
    for (int k = 0; k < 8; ++k) {
        float s = A0[k] + A1[k] + A2[k] + A3[k];
        s += __shfl_xor(s, 16, 64);
        s += __shfl_xor(s, 32, 64);
        A0[k] = s;
    }

    int deg = end - beg;
    float inv = deg > 0 ? 1.0f / (float)deg : 0.f;
    if (q == 0) {
        uint4 r;
        r.x = packbf2(A0[0] * inv, A0[1] * inv);
        r.y = packbf2(A0[2] * inv, A0[3] * inv);
        r.z = packbf2(A0[4] * inv, A0[5] * inv);
        r.w = packbf2(A0[6] * inv, A0[7] * inv);
        ((uint4*)out)[(size_t)n * 16 + ql] = r;
    }
}

// ---------------- MFMA dual-GEMM: out = act([A|F] @ Wp + b) ----------------
// Optionally also emits an fp8 e5m2 copy of the output (gather table for the
// next layer's aggregation).

template <bool LEAKY>
__global__ void mm_kernel(const unsigned short* __restrict__ A,
                          const unsigned short* __restrict__ F,
                          const unsigned short* __restrict__ Wp,
                          const float* __restrict__ bias,
                          unsigned short* __restrict__ out,
                          unsigned char* __restrict__ out8, int N) {
    int wid = threadIdx.x >> 6;
    int lane = threadIdx.x & 63;
    int quad = lane >> 4;
    int m0 = (blockIdx.x * 4 + wid) * 32;

    int rowA0 = m0 + (lane & 15);
    int rowA1 = rowA0 + 16;
    if (rowA0 > N - 1) rowA0 = N - 1;
    if (rowA1 > N - 1) rowA1 = N - 1;

    f32x4 acc[2][8];
#pragma unroll
    for (int t = 0; t < 2; ++t)
#pragma unroll
        for (int nt = 0; nt < 8; ++nt) acc[t][nt] = (f32x4){0.f, 0.f, 0.f, 0.f};

#pragma unroll
    for (int kc = 0; kc < 8; ++kc) {
        const unsigned short* src = (kc < 4) ? (A + kc * 32) : (F + (kc - 4) * 32);
        bf16x8 af0 = *(const bf16x8*)(src + (size_t)rowA0 * D128 + quad * 8);
        bf16x8 af1 = *(const bf16x8*)(src + (size_t)rowA1 * D128 + quad * 8);
        const unsigned short* wp = Wp + ((size_t)kc * 8) * 512 + lane * 8;
#pragma unroll
        for (int nt = 0; nt < 8; ++nt) {
            bf16x8 bf = *(const bf16x8*)(wp + nt * 512);
            acc[0][nt] = __builtin_amdgcn_mfma_f32_16x16x32_bf16(af0, bf, acc[0][nt], 0, 0, 0);
            acc[1][nt] = __builtin_amdgcn_mfma_f32_16x16x32_bf16(af1, bf, acc[1][nt], 0, 0, 0);
        }
    }

#pragma unroll
    for (int nt = 0; nt < 8; ++nt) {
        int col = nt * 16 + (lane & 15);
        float bv = bias[col];
#pragma unroll
        for (int t = 0; t < 2; ++t) {
#pragma unroll
            for (int r = 0; r < 4; ++r) {
                int row = m0 + t * 16 + quad * 4 + r;
                if (row < N) {
                    float v = acc[t][nt][r] + bv;
                    if (LEAKY) v = v >= 0.f ? v : 0.2f * v;
                    out[(size_t)row * D128 + col] = f2bf(v);
                    if (out8) out8[(size_t)row * D128 + col] = f2e5(v);
                }
            }
        }
    }
}

// ---------------- link scoring: 4 pairs per wave (8 gathers in flight) ----------------

__global__ void score_kernel(const int* __restrict__ eli, const unsigned short* __restrict__ h,
                             float* __restrict__ out, int L) {
    int wave = threadIdx.x >> 6;
    int lane = threadIdx.x & 63;
    int l0 = (blockIdx.x * 4 + wave) * 4;
    if (l0 >= L) return;
    const ushort2* h2 = (const ushort2*)h;
    int a[4], b[4];
#pragma unroll
    for (int k = 0; k < 4; ++k) {
        int l = l0 + k;
        if (l > L - 1) l = L - 1;
        a[k] = eli[l];
        b[k] = eli[L + l];
    }
    float p[4];
#pragma unroll
    for (int k = 0; k < 4; ++k) {
        ushort2 u = h2[(size_t)a[k] * 64 + lane];
        ushort2 v = h2[(size_t)b[k] * 64 + lane];
        p[k] = bf2f(u.x) * bf2f(v.x) + bf2f(u.y) * bf2f(v.y);
    }
#pragma unroll
    for (int off = 32; off > 0; off >>= 1) {
#pragma unroll
        for (int k = 0; k < 4; ++k) p[k] += __shfl_down(p[k], off, 64);
    }
    if (lane == 0) {
#pragma unroll
        for (int k = 0; k < 4; ++k) {
            if (l0 + k < L) out[l0 + k] = p[k];
        }
    }
}

// ---------------- host launch ----------------

extern "C" void kernel_launch(void* const* d_in, const int* in_sizes, int n_in,
                              void* d_out, int out_size, void* d_ws, size_t ws_size,
                              hipStream_t stream) {
    const float* x   = (const float*)d_in[0];
    const int*   ei  = (const int*)d_in[1];
    const int*   eli = (const int*)d_in[2];
    const float* W1l = (const float*)d_in[3];
    const float* b1  = (const float*)d_in[4];
    const float* W1r = (const float*)d_in[5];
    const float* W2l = (const float*)d_in[6];
    const float* b2  = (const float*)d_in[7];
    const float* W2r = (const float*)d_in[8];

    const int N = in_sizes[0] / D128;
    const int E = in_sizes[1] / 2;
    const int L = in_sizes[2] / 2;
    const int* srcp = ei;
    const int* dstp = ei + E;
    const int NB = (N + BNODES - 1) >> BSHIFT;   // 196 for N=100000 (<=256)

    char* ws = (char*)d_ws;
    size_t off = 0;
    auto alloc = [&](size_t bytes) -> void* {
        void* p = ws + off;
        off += (bytes + 255) & ~(size_t)255;
        return p;
    };
    int*   rowptr = (int*)alloc((size_t)(N + 1) * sizeof(int));
    int*   gcnt   = (int*)alloc(256 * sizeof(int));
    int*   bbase  = (int*)alloc(257 * sizeof(int));
    int*   bcur   = (int*)alloc(256 * sizeof(int));
    int*   pairs  = (int*)alloc((size_t)E * sizeof(int));
    int*   srcs   = (int*)alloc((size_t)E * sizeof(int));
    unsigned short* xb   = (unsigned short*)alloc((size_t)N * D128 * 2);
    unsigned char*  x8   = (unsigned char*)alloc((size_t)N * D128);
    unsigned char*  h1f8 = (unsigned char*)alloc((size_t)N * D128);
    unsigned short* aggb = (unsigned short*)alloc((size_t)N * D128 * 2);
    unsigned short* h1b  = (unsigned short*)alloc((size_t)N * D128 * 2);
    unsigned short* h2b  = (unsigned short*)alloc((size_t)N * D128 * 2);
    unsigned short* Wp   = (unsigned short*)alloc(2 * 32768 * 2);
    (void)ws_size; (void)n_in; (void)out_size;

    // --- casts + weight repack ---
    int n4 = N * D128 / 4;
    cast_kernel<<<(n4 + 255) / 256, 256, 0, stream>>>(x, xb, x8, n4);
    repack_kernel<<<65536 / 256, 256, 0, stream>>>(W1l, W1r, W2l, W2r, Wp);

    // --- CSR build (bucket counting sort) ---
    hipMemsetAsync(gcnt, 0, 256 * sizeof(int), stream);
    hist_kernel<<<(E + 8191) / 8192, 256, 0, stream>>>(dstp, gcnt, E, NB);
    bucket_scan<<<1, 256, 0, stream>>>(gcnt, bbase, bcur, rowptr, NB, N, E);
    scatter_kernel<<<(E + 1023) / 1024, 256, 0, stream>>>(srcp, dstp, bcur, pairs, E, NB);
    bucket_fill<<<NB, BNODES, 0, stream>>>(pairs, bbase, rowptr, srcs, N);

    // --- layer 1 ---
    agg_kernel<<<(N + 3) / 4, 256, 0, stream>>>(rowptr, srcs, x8, aggb, N);
    mm_kernel<true><<<(N + 127) / 128, 256, 0, stream>>>(aggb, xb, Wp, b1, h1b, h1f8, N);

    // --- layer 2 ---
    agg_kernel<<<(N + 3) / 4, 256, 0, stream>>>(rowptr, srcs, h1f8, aggb, N);
    mm_kernel<false><<<(N + 127) / 128, 256, 0, stream>>>(aggb, h1b, Wp + 32768, b2, h2b,
                                                          (unsigned char*)nullptr, N);

    // --- scoring ---
    score_kernel<<<(L + 15) / 16, 256, 0, stream>>>(eli, h2b, (float*)d_out, L);
}

// Round 8
// 454.391 us; speedup vs baseline: 12.3437x; 1.0211x over previous
//
#include <hip/hip_runtime.h>
#include <hip/hip_fp16.h>

// ---------------------------------------------------------------------------
// LinkPredModel: 2-layer GraphSAGE (mean aggr) + dot-product link scoring.
// N=100000 nodes, D=H=128, E=3.2M edges, L=200k label pairs.
// Round 8: agg decode VALU cut 3x — fp8 e5m2 pairs decoded with 2 bit-ops
// into half2 and accumulated with v_pk_add_f16 (fp16 partials per bank,
// fp32 cross-bank/lane reduction). R7 showed agg flipped to VALU-bound
// (88% VALUBusy) after the fp8 byte-halving.
// ---------------------------------------------------------------------------

#define D128 128
#define BSHIFT 9          // 512 nodes per bucket
#define BNODES 512

typedef __bf16 bf16x8 __attribute__((ext_vector_type(8)));
typedef float  f32x4  __attribute__((ext_vector_type(4)));
typedef _Float16 h2   __attribute__((ext_vector_type(2)));

union uh2cast { unsigned u; h2 h; };
__device__ inline h2 uash2(unsigned u) { uh2cast c; c.u = u; return c.h; }

__device__ inline unsigned short f2bf(float f) {
    unsigned u = __float_as_uint(f);
    u = u + 0x7FFF + ((u >> 16) & 1);   // round-to-nearest-even
    return (unsigned short)(u >> 16);
}
__device__ inline float bf2f(unsigned short s) {
    return __uint_as_float(((unsigned)s) << 16);
}
__device__ inline unsigned packbf2(float lo, float hi) {
    return (unsigned)f2bf(lo) | ((unsigned)f2bf(hi) << 16);
}
// fp8 e5m2 = top byte of fp16 (RNE truncation on encode; decode exact).
__device__ inline unsigned char f2e5(float f) {
    unsigned short h = __half_as_ushort(__float2half(f));  // RNE f32->fp16
    h = (unsigned short)(h + 0x7F + ((h >> 8) & 1));       // RNE fp16->e5m2
    return (unsigned char)(h >> 8);
}

// ---------------- fp32 -> bf16 + fp8 cast (4 elems/thread) ----------------

__global__ void cast_kernel(const float* __restrict__ in, unsigned short* __restrict__ outb,
                            unsigned char* __restrict__ out8, int n4) {
    int i = blockIdx.x * blockDim.x + threadIdx.x;
    if (i >= n4) return;
    float4 v = ((const float4*)in)[i];
    ushort4 ob;
    ob.x = f2bf(v.x); ob.y = f2bf(v.y); ob.z = f2bf(v.z); ob.w = f2bf(v.w);
    ((ushort4*)outb)[i] = ob;
    unsigned p = (unsigned)f2e5(v.x) | ((unsigned)f2e5(v.y) << 8) |
                 ((unsigned)f2e5(v.z) << 16) | ((unsigned)f2e5(v.w) << 24);
    ((unsigned*)out8)[i] = p;
}

// ---------------- weight repack into MFMA B-fragment layout ----------------

__global__ void repack_kernel(const float* __restrict__ W1l, const float* __restrict__ W1r,
                              const float* __restrict__ W2l, const float* __restrict__ W2r,
                              unsigned short* __restrict__ packed) {
    int tid = blockIdx.x * blockDim.x + threadIdx.x;  // [0, 65536)
    int layer = tid >> 15;
    int r = tid & 32767;
    int j    = r & 7;
    int lane = (r >> 3) & 63;
    int nt   = (r >> 9) & 7;
    int kc   = (r >> 12) & 7;
    int k   = kc * 32 + ((lane >> 4) << 3) + j;
    int col = nt * 16 + (lane & 15);
    const float* Wl = layer ? W2l : W1l;
    const float* Wr = layer ? W2r : W1r;
    float v = (k < 128) ? Wl[k * 128 + col] : Wr[(k - 128) * 128 + col];
    packed[tid] = f2bf(v);
}

// ---------------- CSR build: two-level bucket counting sort ----------------

__global__ void hist_kernel(const int* __restrict__ dst, int* __restrict__ gcnt,
                            int E, int NB) {
    __shared__ int h[256];
    int t = threadIdx.x;
    h[t] = 0;
    __syncthreads();
    int base = blockIdx.x * 8192;
#pragma unroll
    for (int k = 0; k < 32; ++k) {
        int e = base + k * 256 + t;
        if (e < E) atomicAdd(&h[dst[e] >> BSHIFT], 1);
    }
    __syncthreads();
    if (t < NB && h[t]) atomicAdd(&gcnt[t], h[t]);
}

__global__ void bucket_scan(const int* __restrict__ gcnt, int* __restrict__ bucket_base,
                            int* __restrict__ bucket_cur, int* __restrict__ rowptr,
                            int NB, int N, int E) {
    __shared__ int sc[256];
    __shared__ int orig[256];
    int t = threadIdx.x;
    int v = (t < NB) ? gcnt[t] : 0;
    orig[t] = v;
    sc[t] = v;
    __syncthreads();
    for (int off = 1; off < 256; off <<= 1) {
        int a = (t >= off) ? sc[t - off] : 0;
        __syncthreads();
        sc[t] += a;
        __syncthreads();
    }
    int ex = sc[t] - orig[t];
    if (t < NB) { bucket_base[t] = ex; bucket_cur[t] = ex; }
    if (t == 0) { bucket_base[NB] = E; rowptr[N] = E; }
}

// packed edge word: (src << 9) | (dst & 511); src < 2^17, so fits in 26 bits.
__global__ void scatter_kernel(const int* __restrict__ src, const int* __restrict__ dst,
                               int* __restrict__ bucket_cur, int* __restrict__ pairs,
                               int E, int NB) {
    __shared__ int hist[256], lscan[256], gbase[256];
    __shared__ int lsrc[1024], ldst[1024];
    int t = threadIdx.x;
    hist[t] = 0;
    __syncthreads();
    int base = blockIdx.x * 1024;
    int total = E - base; if (total > 1024) total = 1024;

    int ms[4], md[4], mb[4], mr[4];
#pragma unroll
    for (int k = 0; k < 4; ++k) {
        int i = k * 256 + t;
        int e = base + i;
        mb[k] = -1;
        if (i < total) {
            ms[k] = src[e];
            md[k] = dst[e];
            mb[k] = md[k] >> BSHIFT;
            mr[k] = atomicAdd(&hist[mb[k]], 1);
        }
    }
    __syncthreads();
    lscan[t] = hist[t];
    __syncthreads();
    for (int off = 1; off < 256; off <<= 1) {
        int a = (t >= off) ? lscan[t - off] : 0;
        __syncthreads();
        lscan[t] += a;
        __syncthreads();
    }
    lscan[t] -= hist[t];
    if (t < NB && hist[t] > 0) gbase[t] = atomicAdd(&bucket_cur[t], hist[t]);
    __syncthreads();
#pragma unroll
    for (int k = 0; k < 4; ++k) {
        if (mb[k] >= 0) {
            int idx = lscan[mb[k]] + mr[k];
            lsrc[idx] = ms[k];
            ldst[idx] = md[k];
        }
    }
    __syncthreads();
#pragma unroll
    for (int k = 0; k < 4; ++k) {
        int i = k * 256 + t;
        if (i < total) {
            int d = ldst[i];
            int b = d >> BSHIFT;
            int pos = gbase[b] + (i - lscan[b]);
            pairs[pos] = (lsrc[i] << BSHIFT) | (d & (BNODES - 1));
        }
    }
}

__global__ void bucket_fill(const int* __restrict__ pairs, const int* __restrict__ bucket_base,
                            int* __restrict__ rowptr, int* __restrict__ srcs, int N) {
    __shared__ int hist[BNODES], excl[BNODES], sc[BNODES];
    int b = blockIdx.x;
    int t = threadIdx.x;      // blockDim = 512
    int node0 = b << BSHIFT;
    int pbeg = bucket_base[b];
    int pend = bucket_base[b + 1];
    hist[t] = 0;
    __syncthreads();
    for (int p = pbeg + t; p < pend; p += BNODES) {
        atomicAdd(&hist[pairs[p] & (BNODES - 1)], 1);
    }
    __syncthreads();
    sc[t] = hist[t];
    __syncthreads();
    for (int off = 1; off < BNODES; off <<= 1) {
        int a = (t >= off) ? sc[t - off] : 0;
        __syncthreads();
        sc[t] += a;
        __syncthreads();
    }
    excl[t] = sc[t] - hist[t];
    int node = node0 + t;
    if (node < N) rowptr[node] = pbeg + excl[t];
    __syncthreads();
    hist[t] = 0;
    __syncthreads();
    for (int p = pbeg + t; p < pend; p += BNODES) {
        int w = pairs[p];
        int dl = w & (BNODES - 1);
        int c = atomicAdd(&hist[dl], 1);
        srcs[pbeg + excl[dl] + c] = ((unsigned)w) >> BSHIFT;
    }
}

// ---------------- mean aggregation: one wave per node, fp8 rows ----------------
// fp8 row = 128B: quarter-wave (16 lanes x uint2) covers one row => one load
// instr fetches 4 edge-rows (512B). 16-edge unroll => 4 independent loads in
// flight. Decode: (v<<8)&0xFF00FF00 and v&0xFF00FF00 are each a half2 of two
// exact fp16 values; accumulate with v_pk_add_f16 (8 VALU per 8 elems).

__device__ inline void pkacc8(h2* A, uint2 v) {
    A[0] += uash2((v.x << 8) & 0xFF00FF00u);   // cols 0,2
    A[1] += uash2(v.x & 0xFF00FF00u);          // cols 1,3
    A[2] += uash2((v.y << 8) & 0xFF00FF00u);   // cols 4,6
    A[3] += uash2(v.y & 0xFF00FF00u);          // cols 5,7
}

__global__ void agg_kernel(const int* __restrict__ rowptr, const int* __restrict__ srcs,
                           const unsigned char* __restrict__ feat8,
                           unsigned short* __restrict__ out, int N) {
    int wave = threadIdx.x >> 6;
    int lane = threadIdx.x & 63;
    int q  = lane >> 4;    // quarter 0..3 -> edge slot within group of 4
    int ql = lane & 15;    // 8B chunk within 128B row
    int n = blockIdx.x * 4 + wave;
    if (n >= N) return;
    int beg = rowptr[n];
    int end = rowptr[n + 1];
    const uint2* f = (const uint2*)feat8;   // 16 uint2 per 128B row

    h2 A0[4], A1[4], A2[4], A3[4];
    h2 z; z[0] = (_Float16)0.f; z[1] = (_Float16)0.f;
#pragma unroll
    for (int k = 0; k < 4; ++k) { A0[k] = z; A1[k] = z; A2[k] = z; A3[k] = z; }

    int j = beg;
    for (; j + 16 <= end; j += 16) {
        int e0 = srcs[j + q];
        int e1 = srcs[j + 4 + q];
        int e2 = srcs[j + 8 + q];
        int e3 = srcs[j + 12 + q];
        uint2 v0 = f[(size_t)e0 * 16 + ql];
        uint2 v1 = f[(size_t)e1 * 16 + ql];
        uint2 v2 = f[(size_t)e2 * 16 + ql];
        uint2 v3 = f[(size_t)e3 * 16 + ql];
        pkacc8(A0, v0);
        pkacc8(A1, v1);
        pkacc8(A2, v2);
        pkacc8(A3, v3);
    }
    for (; j + 4 <= end; j += 4) {
        int e = srcs[j + q];
        uint2 v = f[(size_t)e * 16 + ql];
        pkacc8(A0, v);
    }
    int rem = end - j;
    if (q < rem) {
        int e = srcs[j + q];
        uint2 v = f[(size_t)e * 16 + ql];
        pkacc8(A1, v);
    }

    // combine banks in fp32: p=0 -> cols 0,2 ; 1 -> 1,3 ; 2 -> 4,6 ; 3 -> 5,7
    float c[8];
#pragma unroll
    for (int p = 0; p < 4; ++p) {
        float lo = (float)A0[p][0] + (float)A1[p][0] + (float)A2[p][0] + (float)A3[p][0];
        float hi = (float)A0[p][1] + (float)A1[p][1] + (float)A2[p][1] + (float)A3[p][1];
        int base = (p >> 1) * 4 + (p & 1);
        c[base] = lo;
        c[base + 2] = hi;
    }

#pragma unroll
    for (int k = 0; k < 8; ++k) {
        c[k] += __shfl_xor(c[k], 16, 64);
        c[k] += __shfl_xor(c[k], 32, 64);
    }

    int deg = end - beg;
    float inv = deg > 0 ? 1.0f / (float)deg : 0.f;
    if (q == 0) {
        uint4 r;
        r.x = packbf2(c[0] * inv, c[1] * inv);
        r.y = packbf2(c[2] * inv, c[3] * inv);
        r.z = packbf2(c[4] * inv, c[5] * inv);
        r.w = packbf2(c[6] * inv, c[7] * inv);
        ((uint4*)out)[(size_t)n * 16 + ql] = r;
    }
}

// ---------------- MFMA dual-GEMM: out = act([A|F] @ Wp + b) ----------------
// Optionally also emits an fp8 e5m2 copy of the output (gather table for the
// next layer's aggregation).

template <bool LEAKY>
__global__ void mm_kernel(const unsigned short* __restrict__ A,
                          const unsigned short* __restrict__ F,
                          const unsigned short* __restrict__ Wp,
                          const float* __restrict__ bias,
                          unsigned short* __restrict__ out,
                          unsigned char* __restrict__ out8, int N) {
    int wid = threadIdx.x >> 6;
    int lane = threadIdx.x & 63;
    int quad = lane >> 4;
    int m0 = (blockIdx.x * 4 + wid) * 32;

    int rowA0 = m0 + (lane & 15);
    int rowA1 = rowA0 + 16;
    if (rowA0 > N - 1) rowA0 = N - 1;
    if (rowA1 > N - 1) rowA1 = N - 1;

    f32x4 acc[2][8];
#pragma unroll
    for (int t = 0; t < 2; ++t)
#pragma unroll
        for (int nt = 0; nt < 8; ++nt) acc[t][nt] = (f32x4){0.f, 0.f, 0.f, 0.f};

#pragma unroll
    for (int kc = 0; kc < 8; ++kc) {
        const unsigned short* src = (kc < 4) ? (A + kc * 32) : (F + (kc - 4) * 32);
        bf16x8 af0 = *(const bf16x8*)(src + (size_t)rowA0 * D128 + quad * 8);
        bf16x8 af1 = *(const bf16x8*)(src + (size_t)rowA1 * D128 + quad * 8);
        const unsigned short* wp = Wp + ((size_t)kc * 8) * 512 + lane * 8;
#pragma unroll
        for (int nt = 0; nt < 8; ++nt) {
            bf16x8 bf = *(const bf16x8*)(wp + nt * 512);
            acc[0][nt] = __builtin_amdgcn_mfma_f32_16x16x32_bf16(af0, bf, acc[0][nt], 0, 0, 0);
            acc[1][nt] = __builtin_amdgcn_mfma_f32_16x16x32_bf16(af1, bf, acc[1][nt], 0, 0, 0);
        }
    }

#pragma unroll
    for (int nt = 0; nt < 8; ++nt) {
        int col = nt * 16 + (lane & 15);
        float bv = bias[col];
#pragma unroll
        for (int t = 0; t < 2; ++t) {
#pragma unroll
            for (int r = 0; r < 4; ++r) {
                int row = m0 + t * 16 + quad * 4 + r;
                if (row < N) {
                    float v = acc[t][nt][r] + bv;
                    if (LEAKY) v = v >= 0.f ? v : 0.2f * v;
                    out[(size_t)row * D128 + col] = f2bf(v);
                    if (out8) out8[(size_t)row * D128 + col] = f2e5(v);
                }
            }
        }
    }
}

// ---------------- link scoring: 4 pairs per wave (8 gathers in flight) ----------------

__global__ void score_kernel(const int* __restrict__ eli, const unsigned short* __restrict__ h,
                             float* __restrict__ out, int L) {
    int wave = threadIdx.x >> 6;
    int lane = threadIdx.x & 63;
    int l0 = (blockIdx.x * 4 + wave) * 4;
    if (l0 >= L) return;
    const ushort2* h2p = (const ushort2*)h;
    int a[4], b[4];
#pragma unroll
    for (int k = 0; k < 4; ++k) {
        int l = l0 + k;
        if (l > L - 1) l = L - 1;
        a[k] = eli[l];
        b[k] = eli[L + l];
    }
    float p[4];
#pragma unroll
    for (int k = 0; k < 4; ++k) {
        ushort2 u = h2p[(size_t)a[k] * 64 + lane];
        ushort2 v = h2p[(size_t)b[k] * 64 + lane];
        p[k] = bf2f(u.x) * bf2f(v.x) + bf2f(u.y) * bf2f(v.y);
    }
#pragma unroll
    for (int off = 32; off > 0; off >>= 1) {
#pragma unroll
        for (int k = 0; k < 4; ++k) p[k] += __shfl_down(p[k], off, 64);
    }
    if (lane == 0) {
#pragma unroll
        for (int k = 0; k < 4; ++k) {
            if (l0 + k < L) out[l0 + k] = p[k];
        }
    }
}

// ---------------- host launch ----------------

extern "C" void kernel_launch(void* const* d_in, const int* in_sizes, int n_in,
                              void* d_out, int out_size, void* d_ws, size_t ws_size,
                              hipStream_t stream) {
    const float* x   = (const float*)d_in[0];
    const int*   ei  = (const int*)d_in[1];
    const int*   eli = (const int*)d_in[2];
    const float* W1l = (const float*)d_in[3];
    const float* b1  = (const float*)d_in[4];
    const float* W1r = (const float*)d_in[5];
    const float* W2l = (const float*)d_in[6];
    const float* b2  = (const float*)d_in[7];
    const float* W2r = (const float*)d_in[8];

    const int N = in_sizes[0] / D128;
    const int E = in_sizes[1] / 2;
    const int L = in_sizes[2] / 2;
    const int* srcp = ei;
    const int* dstp = ei + E;
    const int NB = (N + BNODES - 1) >> BSHIFT;   // 196 for N=100000 (<=256)

    char* ws = (char*)d_ws;
    size_t off = 0;
    auto alloc = [&](size_t bytes) -> void* {
        void* p = ws + off;
        off += (bytes + 255) & ~(size_t)255;
        return p;
    };
    int*   rowptr = (int*)alloc((size_t)(N + 1) * sizeof(int));
    int*   gcnt   = (int*)alloc(256 * sizeof(int));
    int*   bbase  = (int*)alloc(257 * sizeof(int));
    int*   bcur   = (int*)alloc(256 * sizeof(int));
    int*   pairs  = (int*)alloc((size_t)E * sizeof(int));
    int*   srcs   = (int*)alloc((size_t)E * sizeof(int));
    unsigned short* xb   = (unsigned short*)alloc((size_t)N * D128 * 2);
    unsigned char*  x8   = (unsigned char*)alloc((size_t)N * D128);
    unsigned char*  h1f8 = (unsigned char*)alloc((size_t)N * D128);
    unsigned short* aggb = (unsigned short*)alloc((size_t)N * D128 * 2);
    unsigned short* h1b  = (unsigned short*)alloc((size_t)N * D128 * 2);
    unsigned short* h2b  = (unsigned short*)alloc((size_t)N * D128 * 2);
    unsigned short* Wp   = (unsigned short*)alloc(2 * 32768 * 2);
    (void)ws_size; (void)n_in; (void)out_size;

    // --- casts + weight repack ---
    int n4 = N * D128 / 4;
    cast_kernel<<<(n4 + 255) / 256, 256, 0, stream>>>(x, xb, x8, n4);
    repack_kernel<<<65536 / 256, 256, 0, stream>>>(W1l, W1r, W2l, W2r, Wp);

    // --- CSR build (bucket counting sort) ---
    hipMemsetAsync(gcnt, 0, 256 * sizeof(int), stream);
    hist_kernel<<<(E + 8191) / 8192, 256, 0, stream>>>(dstp, gcnt, E, NB);
    bucket_scan<<<1, 256, 0, stream>>>(gcnt, bbase, bcur, rowptr, NB, N, E);
    scatter_kernel<<<(E + 1023) / 1024, 256, 0, stream>>>(srcp, dstp, bcur, pairs, E, NB);
    bucket_fill<<<NB, BNODES, 0, stream>>>(pairs, bbase, rowptr, srcs, N);

    // --- layer 1 ---
    agg_kernel<<<(N + 3) / 4, 256, 0, stream>>>(rowptr, srcs, x8, aggb, N);
    mm_kernel<true><<<(N + 127) / 128, 256, 0, stream>>>(aggb, xb, Wp, b1, h1b, h1f8, N);

    // --- layer 2 ---
    agg_kernel<<<(N + 3) / 4, 256, 0, stream>>>(rowptr, srcs, h1f8, aggb, N);
    mm_kernel<false><<<(N + 127) / 128, 256, 0, stream>>>(aggb, h1b, Wp + 32768, b2, h2b,
                                                          (unsigned char*)nullptr, N);

    // --- scoring ---
    score_kernel<<<(L + 15) / 16, 256, 0, stream>>>(eli, h2b, (float*)d_out, L);
}